// Round 16
// baseline (572.552 us; speedup 1.0000x reference)
//
#include <hip/hip_runtime.h>

#define NN 50000      // nodes
#define NN2 50048     // nodes padded to 64
#define NE 800000     // edges
#define NB 128        // graphs / batch
#define SD 64         // state dim / node dim
#define GH 128        // gnn layer1 width
#define GD 64         // gnn layer2 width
#define HID 256       // actor hidden
#define AD 8          // action dim
#define CPAD 53248    // cnt/offs padded: 1024*52
#define NC 8          // histogram copies
#define EB 391        // edge blocks (2048 edges each)
#define MB 782        // node tile blocks (64 rows each)
#define BST 66        // B-tile LDS stride (shorts), 33 ints: conflict-free
#define BST2 130      // mlp2 B-tile stride (shorts), 65 ints

static inline size_t align256(size_t x){ return (x + 255) & ~size_t(255); }

typedef __attribute__((ext_vector_type(8))) short short8v;
typedef __attribute__((ext_vector_type(4))) float f32x4;
typedef __attribute__((ext_vector_type(2))) float f32x2;

__device__ inline unsigned short f2bf(float f){  // RNE
  unsigned u = __builtin_bit_cast(unsigned, f);
  return (unsigned short)((u + 0x7FFFu + ((u >> 16) & 1u)) >> 16);
}
__device__ inline float bf2f(unsigned short h){
  return __builtin_bit_cast(float, ((unsigned)h) << 16);
}
__device__ inline int pk2bf(float a, float b){
  return (int)((unsigned)f2bf(a) | ((unsigned)f2bf(b) << 16));
}
// fp8 e4m3 HW converts
__device__ inline f32x2 fp8x2_to_f32(unsigned short u){
  return __builtin_amdgcn_cvt_pk_f32_fp8((int)u, false);
}
__device__ inline unsigned char f32_to_fp8(float v){
  return (unsigned char)(__builtin_amdgcn_cvt_pk_fp8_f32(v, v, 0, false) & 0xFF);
}
__device__ inline unsigned pack4_fp8(float a, float b, float c, float d){
  int w = __builtin_amdgcn_cvt_pk_fp8_f32(a, b, 0, false);
  w = __builtin_amdgcn_cvt_pk_fp8_f32(c, d, w, true);
  return (unsigned)w;
}

// ------- fused: hist (blocks [0,EB), 8-copy) ∥ layer-1 GEMM (blocks [EB,EB+4*MB)) ----
__global__ __launch_bounds__(256)
void k_histgemm1(const int* __restrict__ edst, int* __restrict__ cntc,
                 unsigned short* __restrict__ rank,
                 const float* __restrict__ x, const float* __restrict__ w1,
                 unsigned char* __restrict__ fA8, unsigned char* __restrict__ fB8)
{
  if (blockIdx.x < EB){
    int* cc = cntc + (blockIdx.x & (NC-1)) * CPAD;
    int e = blockIdx.x*2048 + threadIdx.x;
    #pragma unroll
    for (int j = 0; j < 8; ++j){
      int ee = e + j*256;
      if (ee < NE) rank[ee] = (unsigned short)atomicAdd(&cc[edst[ee]], 1);
    }
    return;
  }
  int idx = blockIdx.x - EB;           // 0..3127
  int m0 = (idx >> 2) * 64;
  int n0 = (idx & 1) * 64;
  int z  = (idx >> 1) & 1;
  const float* W = w1 + (size_t)z*64*GH;
  unsigned char* Out = z ? fB8 : fA8;

  __shared__ short Ah[64*40];
  __shared__ short Bh[32*BST];          // [k][n], stride 66
  __shared__ float Ts[64*65];
  int tid = threadIdx.x;
  int w = tid >> 6, lane = tid & 63, l15 = tid & 15, quad = lane >> 4;
  f32x4 acc[4];
  #pragma unroll
  for (int t = 0; t < 4; ++t) acc[t] = (f32x4){0.f,0.f,0.f,0.f};

  #pragma unroll
  for (int k0 = 0; k0 < 64; k0 += 32){
    #pragma unroll
    for (int i = 0; i < 2; ++i){       // A: x fp32 -> bf16 [m][k]
      int s = tid + i*256;
      int m = s >> 3, q = s & 7;
      float4 v = make_float4(0.f,0.f,0.f,0.f);
      if (m0 + m < NN) v = *reinterpret_cast<const float4*>(&x[(size_t)(m0+m)*SD + k0 + q*4]);
      short4 h4;
      h4.x = (short)f2bf(v.x); h4.y = (short)f2bf(v.y);
      h4.z = (short)f2bf(v.z); h4.w = (short)f2bf(v.w);
      *reinterpret_cast<short4*>(&Ah[m*40 + q*4]) = h4;
    }
    #pragma unroll
    for (int i = 0; i < 2; ++i){       // B: W fp32 -> bf16 [k][n] (conflict-free)
      int s = tid + i*256;
      int r = s >> 4, cq = s & 15;
      float4 v = *reinterpret_cast<const float4*>(&W[(size_t)(k0+r)*GH + n0 + cq*4]);
      *reinterpret_cast<int*>(&Bh[r*BST + cq*4])     = pk2bf(v.x, v.y);
      *reinterpret_cast<int*>(&Bh[r*BST + cq*4 + 2]) = pk2bf(v.z, v.w);
    }
    __syncthreads();
    short8v ah = *reinterpret_cast<short8v*>(&Ah[(w*16 + l15)*40 + quad*8]);
    #pragma unroll
    for (int t = 0; t < 4; ++t){
      short8v bh;
      #pragma unroll
      for (int j = 0; j < 8; ++j)
        bh[j] = Bh[(quad*8 + j)*BST + t*16 + l15];
      acc[t] = __builtin_amdgcn_mfma_f32_16x16x32_bf16(ah, bh, acc[t], 0, 0, 0);
    }
    __syncthreads();
  }
  #pragma unroll
  for (int r = 0; r < 4; ++r){
    int ml = w*16 + quad*4 + r;
    #pragma unroll
    for (int t = 0; t < 4; ++t)
      Ts[ml*65 + t*16 + l15] = acc[t][r];
  }
  __syncthreads();
  int row = tid >> 2, seg = tid & 3;
  const float* tr = &Ts[row*65 + seg*16];
  uint4 o;
  o.x = pack4_fp8(tr[0], tr[1], tr[2], tr[3]);
  o.y = pack4_fp8(tr[4], tr[5], tr[6], tr[7]);
  o.z = pack4_fp8(tr[8], tr[9], tr[10], tr[11]);
  o.w = pack4_fp8(tr[12], tr[13], tr[14], tr[15]);
  *reinterpret_cast<uint4*>(&Out[(size_t)(m0+row)*GH + n0 + seg*16]) = o;
}

// scan over 8-copy histogram, spill-free: tot[n] = Σc cntc[c][n];
// basec[c][n] = global exclusive prefix with per-copy interleave.
__global__ __launch_bounds__(1024)
void k_scan1(const int* __restrict__ cntc, int* __restrict__ basec,
             int* __restrict__ tot){
  __shared__ int sm[1024];
  int t = threadIdx.x;
  int base = t*52;
  int s = 0;
  for (int j = 0; j < 13; ++j){
    int4 a = make_int4(0,0,0,0);
    #pragma unroll
    for (int c = 0; c < NC; ++c){
      int4 v = *reinterpret_cast<const int4*>(&cntc[c*CPAD + base + j*4]);
      a.x += v.x; a.y += v.y; a.z += v.z; a.w += v.w;
    }
    *reinterpret_cast<int4*>(&tot[base + j*4]) = a;
    s += a.x + a.y + a.z + a.w;
  }
  sm[t] = s; __syncthreads();
  for (int d = 1; d < 1024; d <<= 1){
    int add = (t >= d) ? sm[t - d] : 0;
    __syncthreads();
    sm[t] += add;
    __syncthreads();
  }
  int run = sm[t] - s;   // exclusive
  for (int n = base; n < base + 52; ++n){
    #pragma unroll
    for (int c = 0; c < NC; ++c){
      int v = cntc[c*CPAD + n];
      basec[c*CPAD + n] = run;
      run += v;
    }
  }
}

__global__ void k_place(const int* __restrict__ esrc, const int* __restrict__ edst,
                        const int* __restrict__ basec,
                        const unsigned short* __restrict__ rank,
                        unsigned short* __restrict__ ssrc){
  int e = blockIdx.x*2048 + threadIdx.x;
  #pragma unroll
  for (int j = 0; j < 8; ++j){
    int ee = e + j*256;
    if (ee < NE){
      const int* bc = basec + ((ee >> 11) & (NC-1)) * CPAD;
      ssrc[bc[edst[ee]] + (int)rank[ee]] = (unsigned short)esrc[ee];
    }
  }
}

// ------- edge agg layer 1: fp8 gather, 4 ch/lane (32 lanes/node), 8 nodes/block ------
__global__ __launch_bounds__(256)
void k_edge1(const unsigned char* __restrict__ A, const unsigned char* __restrict__ Bm,
             const float* __restrict__ b1, const int* __restrict__ offs,
             const int* __restrict__ cnt, const unsigned short* __restrict__ ssrc,
             unsigned short* __restrict__ S)
{
  int v = blockIdx.x*8 + (threadIdx.x >> 5);
  int c4 = threadIdx.x & 31;          // channels 4*c4 .. 4*c4+3
  int beg = offs[v], n = cnt[v];
  float s0=0.f, s1=0.f, s2=0.f, s3=0.f;
  if (n > 0){
    unsigned au = *reinterpret_cast<const unsigned*>(&A[(size_t)v*GH + 4*c4]);
    f32x2 a01 = fp8x2_to_f32((unsigned short)(au & 0xFFFFu));
    f32x2 a23 = fp8x2_to_f32((unsigned short)(au >> 16));
    float4 bb = *reinterpret_cast<const float4*>(&b1[4*c4]);
    float ax0 = a01.x + bb.x, ax1 = a01.y + bb.y;
    float ax2 = a23.x + bb.z, ax3 = a23.y + bb.w;
    for (int i = 0; i < n; i += 8){
      int ss[8];
      #pragma unroll
      for (int j = 0; j < 8; ++j)
        ss[j] = (i + j < n) ? (int)ssrc[beg + i + j] : (int)ssrc[beg];
      unsigned bu[8];
      #pragma unroll
      for (int j = 0; j < 8; ++j)
        bu[j] = *reinterpret_cast<const unsigned*>(&Bm[(size_t)ss[j]*GH + 4*c4]);
      #pragma unroll
      for (int j = 0; j < 8; ++j){
        f32x2 b01 = fp8x2_to_f32((unsigned short)(bu[j] & 0xFFFFu));
        f32x2 b23 = fp8x2_to_f32((unsigned short)(bu[j] >> 16));
        float live = (i + j < n) ? 1.f : 0.f;
        s0 += live * fmaxf(ax0 + b01.x, 0.f);
        s1 += live * fmaxf(ax1 + b01.y, 0.f);
        s2 += live * fmaxf(ax2 + b23.x, 0.f);
        s3 += live * fmaxf(ax3 + b23.y, 0.f);
      }
    }
  }
  ushort4 o; o.x = f2bf(s0); o.y = f2bf(s1); o.z = f2bf(s2); o.w = f2bf(s3);
  *reinterpret_cast<ushort4*>(&S[(size_t)v*GH + 4*c4]) = o;
}

// ---- fused GNN-layer MLP: h = relu(mean(fS@W2)); C|D = h@W3 (fp8 out), fp32 W ----
__global__ __launch_bounds__(256)
void k_mlp2(const unsigned short* __restrict__ In,   // fS [NN,128] bf16
            const float* __restrict__ W2,            // [128,128] fp32
            const float* __restrict__ W3,            // [256,64] fp32
            const int* __restrict__ cnt, const float* __restrict__ b2,
            unsigned char* __restrict__ fC, unsigned char* __restrict__ fD)
{
  __shared__ short Ah[64*40];
  __shared__ short Bh[32*BST2];        // [k][n(=128)], stride 130
  __shared__ unsigned short Hs[64*136];
  int tid = threadIdx.x;
  int w = tid >> 6, lane = tid & 63, l15 = tid & 15, quad = lane >> 4;
  int m0 = blockIdx.x*64;

  f32x4 acc[8];
  #pragma unroll
  for (int t = 0; t < 8; ++t) acc[t] = (f32x4){0.f,0.f,0.f,0.f};

  for (int k0 = 0; k0 < 128; k0 += 32){
    { int m = tid >> 2, o = tid & 3;
      short8v v = (short8v)(short)0;
      if (m0 + m < NN)
        v = *reinterpret_cast<const short8v*>(&In[(size_t)(m0+m)*GH + k0 + o*8]);
      *reinterpret_cast<short8v*>(&Ah[m*40 + o*8]) = v;
    }
    #pragma unroll
    for (int i = 0; i < 4; ++i){       // W2 fp32 -> bf16 [k][n] (conflict-free)
      int s = tid + i*256;             // 0..1023
      int r = s >> 5, cq = s & 31;
      float4 v = *reinterpret_cast<const float4*>(&W2[(size_t)(k0+r)*GH + cq*4]);
      *reinterpret_cast<int*>(&Bh[r*BST2 + cq*4])     = pk2bf(v.x, v.y);
      *reinterpret_cast<int*>(&Bh[r*BST2 + cq*4 + 2]) = pk2bf(v.z, v.w);
    }
    __syncthreads();
    short8v ah = *reinterpret_cast<short8v*>(&Ah[(w*16 + l15)*40 + quad*8]);
    #pragma unroll
    for (int t = 0; t < 8; ++t){
      short8v bh;
      #pragma unroll
      for (int j = 0; j < 8; ++j)
        bh[j] = Bh[(quad*8 + j)*BST2 + t*16 + l15];
      acc[t] = __builtin_amdgcn_mfma_f32_16x16x32_bf16(ah, bh, acc[t], 0, 0, 0);
    }
    __syncthreads();
  }
  #pragma unroll
  for (int r = 0; r < 4; ++r){
    int ml = w*16 + quad*4 + r;
    int m = m0 + ml;
    float fcnt = 0.f, inv = 1.f;
    if (m < NN){ fcnt = (float)cnt[m]; inv = 1.f / fmaxf(fcnt, 1.f); }
    #pragma unroll
    for (int t = 0; t < 8; ++t){
      int col = t*16 + l15;
      float v = (acc[t][r] + fcnt * b2[col]) * inv;
      Hs[ml*136 + col] = f2bf(fmaxf(v, 0.f));
    }
  }
  __syncthreads();

  f32x4 acc2[8];
  #pragma unroll
  for (int t = 0; t < 8; ++t) acc2[t] = (f32x4){0.f,0.f,0.f,0.f};
  for (int k0 = 0; k0 < 128; k0 += 32){
    #pragma unroll
    for (int i = 0; i < 4; ++i){       // W3 fp32 halves -> bf16 [k][n] (n<64=C)
      int s = tid + i*256;             // 0..1023
      int r = s >> 5, cq = s & 31;
      int half = cq >> 4, cg = cq & 15;
      float4 v = *reinterpret_cast<const float4*>(&W3[(size_t)(half*128 + k0 + r)*GD + cg*4]);
      *reinterpret_cast<int*>(&Bh[r*BST2 + cq*4])     = pk2bf(v.x, v.y);
      *reinterpret_cast<int*>(&Bh[r*BST2 + cq*4 + 2]) = pk2bf(v.z, v.w);
    }
    __syncthreads();
    short8v ah = *reinterpret_cast<short8v*>(&Hs[(w*16 + l15)*136 + k0 + quad*8]);
    #pragma unroll
    for (int t = 0; t < 8; ++t){
      short8v bh;
      #pragma unroll
      for (int j = 0; j < 8; ++j)
        bh[j] = Bh[(quad*8 + j)*BST2 + t*16 + l15];
      acc2[t] = __builtin_amdgcn_mfma_f32_16x16x32_bf16(ah, bh, acc2[t], 0, 0, 0);
    }
    __syncthreads();
  }
  #pragma unroll
  for (int r = 0; r < 4; ++r){
    int m = m0 + w*16 + quad*4 + r;
    if (m >= NN) continue;
    #pragma unroll
    for (int t = 0; t < 8; ++t){
      int col = t*16 + l15;
      unsigned char o = f32_to_fp8(acc2[t][r]);
      if (col < 64) fC[(size_t)m*GD + col] = o;
      else          fD[(size_t)m*GD + col - 64] = o;
    }
  }
}

// ------- edge agg layer 2: fp8 gather, 4 ch/lane (16 lanes/node), 16 nodes/block -----
__global__ __launch_bounds__(256)
void k_edge2(const unsigned char* __restrict__ C, const unsigned char* __restrict__ D,
             const float* __restrict__ b1, const int* __restrict__ offs,
             const int* __restrict__ cnt, const unsigned short* __restrict__ ssrc,
             unsigned short* __restrict__ S2)
{
  int v = blockIdx.x*16 + (threadIdx.x >> 4);
  int c4 = threadIdx.x & 15;          // channels 4*c4 .. 4*c4+3
  int beg = offs[v], n = cnt[v];
  float s0=0.f, s1=0.f, s2=0.f, s3=0.f;
  if (n > 0){
    unsigned au = *reinterpret_cast<const unsigned*>(&C[(size_t)v*GD + 4*c4]);
    f32x2 a01 = fp8x2_to_f32((unsigned short)(au & 0xFFFFu));
    f32x2 a23 = fp8x2_to_f32((unsigned short)(au >> 16));
    float4 bb = *reinterpret_cast<const float4*>(&b1[4*c4]);
    float ax0 = a01.x + bb.x, ax1 = a01.y + bb.y;
    float ax2 = a23.x + bb.z, ax3 = a23.y + bb.w;
    for (int i = 0; i < n; i += 8){
      int ss[8];
      #pragma unroll
      for (int j = 0; j < 8; ++j)
        ss[j] = (i + j < n) ? (int)ssrc[beg + i + j] : (int)ssrc[beg];
      unsigned du[8];
      #pragma unroll
      for (int j = 0; j < 8; ++j)
        du[j] = *reinterpret_cast<const unsigned*>(&D[(size_t)ss[j]*GD + 4*c4]);
      #pragma unroll
      for (int j = 0; j < 8; ++j){
        f32x2 d01 = fp8x2_to_f32((unsigned short)(du[j] & 0xFFFFu));
        f32x2 d23 = fp8x2_to_f32((unsigned short)(du[j] >> 16));
        float live = (i + j < n) ? 1.f : 0.f;
        s0 += live * fmaxf(ax0 + d01.x, 0.f);
        s1 += live * fmaxf(ax1 + d01.y, 0.f);
        s2 += live * fmaxf(ax2 + d23.x, 0.f);
        s3 += live * fmaxf(ax3 + d23.y, 0.f);
      }
    }
  }
  ushort4 o; o.x = f2bf(s0); o.y = f2bf(s1); o.z = f2bf(s2); o.w = f2bf(s3);
  *reinterpret_cast<ushort4*>(&S2[(size_t)v*GD + 4*c4]) = o;
}

// ------- final GEMM: h2 = mean(fS2@W4)+b, graph-sum epilogue into gsum (fp32 W) ------
__global__ __launch_bounds__(256)
void k_gemm4gs(const unsigned short* __restrict__ In,  // fS2 [NN,64] bf16
               const float* __restrict__ W4,           // [64,64] fp32
               const int* __restrict__ cnt, const float* __restrict__ bias,
               const int* __restrict__ nb, float* __restrict__ gsum)
{
  __shared__ short Ah[64*40];
  __shared__ short Bh[32*BST];         // [k][n], stride 66
  __shared__ float Ts[64*65];
  int tid = threadIdx.x;
  int w = tid >> 6, lane = tid & 63, l15 = tid & 15, quad = lane >> 4;
  int m0 = blockIdx.x*64;
  f32x4 acc[4];
  #pragma unroll
  for (int t = 0; t < 4; ++t) acc[t] = (f32x4){0.f,0.f,0.f,0.f};

  #pragma unroll
  for (int k0 = 0; k0 < 64; k0 += 32){
    { int m = tid >> 2, o = tid & 3;
      short8v v = (short8v)(short)0;
      if (m0 + m < NN)
        v = *reinterpret_cast<const short8v*>(&In[(size_t)(m0+m)*GD + k0 + o*8]);
      *reinterpret_cast<short8v*>(&Ah[m*40 + o*8]) = v;
    }
    #pragma unroll
    for (int i = 0; i < 2; ++i){       // W4 fp32 -> bf16 [k][n] (conflict-free)
      int s = tid + i*256;
      int r = s >> 4, cq = s & 15;
      float4 v = *reinterpret_cast<const float4*>(&W4[(size_t)(k0+r)*GD + cq*4]);
      *reinterpret_cast<int*>(&Bh[r*BST + cq*4])     = pk2bf(v.x, v.y);
      *reinterpret_cast<int*>(&Bh[r*BST + cq*4 + 2]) = pk2bf(v.z, v.w);
    }
    __syncthreads();
    short8v ah = *reinterpret_cast<short8v*>(&Ah[(w*16 + l15)*40 + quad*8]);
    #pragma unroll
    for (int t = 0; t < 4; ++t){
      short8v bh;
      #pragma unroll
      for (int j = 0; j < 8; ++j)
        bh[j] = Bh[(quad*8 + j)*BST + t*16 + l15];
      acc[t] = __builtin_amdgcn_mfma_f32_16x16x32_bf16(ah, bh, acc[t], 0, 0, 0);
    }
    __syncthreads();
  }
  #pragma unroll
  for (int r = 0; r < 4; ++r){
    int ml = w*16 + quad*4 + r;
    int m = m0 + ml;
    float fcnt = 0.f, inv = 1.f;
    if (m < NN){ fcnt = (float)cnt[m]; inv = 1.f / fmaxf(fcnt, 1.f); }
    #pragma unroll
    for (int t = 0; t < 4; ++t){
      int n = t*16 + l15;
      Ts[ml*65 + n] = (acc[t][r] + fcnt * bias[n]) * inv;
    }
  }
  __syncthreads();
  int col = tid & 63, rg = tid >> 6;
  float a = 0.f; int cur = -1;
  for (int rr = rg*16; rr < rg*16 + 16; ++rr){
    int m = m0 + rr; if (m >= NN) break;
    int g = nb[m];
    if (g != cur){ if (cur >= 0) atomicAdd(&gsum[cur*GD + col], a); cur = g; a = 0.f; }
    a += Ts[rr*65 + col];
  }
  if (cur >= 0) atomicAdd(&gsum[cur*GD + col], a);
}

// ---------------- actor head: one block per batch row (divide fused here) -----
__global__ __launch_bounds__(256)
void k_head(const float* __restrict__ state, const float* __restrict__ gsum,
            const int* __restrict__ nb,
            const float* __restrict__ fc1w, const float* __restrict__ fc1b,
            const float* __restrict__ fc2w, const float* __restrict__ fc2b,
            const float* __restrict__ mw, const float* __restrict__ mb,
            const float* __restrict__ lw, const float* __restrict__ lb,
            float* __restrict__ out)
{
  int b = blockIdx.x, t = threadIdx.x;
  __shared__ float z[SD + GD];
  __shared__ float h1[HID];
  __shared__ float h2[HID];
  __shared__ int bounds[2];
  if (t < 2){
    int target = b + t;
    int lo = 0, hi = NN;
    while (lo < hi){ int mid = (lo + hi) >> 1; if (nb[mid] < target) lo = mid + 1; else hi = mid; }
    bounds[t] = lo;
  }
  if (t < SD) z[t] = state[b*SD + t];
  __syncthreads();
  if (t >= SD && t < SD + GD){
    float n = (float)(bounds[1] - bounds[0]);
    z[t] = gsum[b*GD + (t - SD)] / fmaxf(n, 1.f);
  }
  __syncthreads();
  float acc = fc1b[t];
  for (int k = 0; k < SD + GD; ++k) acc = fmaf(z[k], fc1w[k*HID + t], acc);
  h1[t] = fmaxf(acc, 0.f);
  __syncthreads();
  acc = fc2b[t];
  for (int k = 0; k < HID; ++k) acc = fmaf(h1[k], fc2w[k*HID + t], acc);
  h2[t] = fmaxf(acc, 0.f);
  __syncthreads();
  if (t < AD){
    float m = mb[t];
    for (int k = 0; k < HID; ++k) m = fmaf(h2[k], mw[k*AD + t], m);
    out[b*AD + t] = m;
  } else if (t < 2*AD){
    int j = t - AD;
    float l = lb[j];
    for (int k = 0; k < HID; ++k) l = fmaf(h2[k], lw[k*AD + j], l);
    out[NB*AD + b*AD + j] = fminf(fmaxf(l, -20.f), 2.f);
  }
}

extern "C" void kernel_launch(void* const* d_in, const int* in_sizes, int n_in,
                              void* d_out, int out_size, void* d_ws, size_t ws_size,
                              hipStream_t stream)
{
  const float* state = (const float*)d_in[0];
  const float* x     = (const float*)d_in[1];
  const int*   eidx  = (const int*)  d_in[2];
  const int*   nb    = (const int*)  d_in[3];
  const float* g1w1  = (const float*)d_in[4];
  const float* g1b1  = (const float*)d_in[5];
  const float* g1w2  = (const float*)d_in[6];
  const float* g1b2  = (const float*)d_in[7];
  const float* g2w1  = (const float*)d_in[8];
  const float* g2b1  = (const float*)d_in[9];
  const float* g2w2  = (const float*)d_in[10];
  const float* g2b2  = (const float*)d_in[11];
  const float* fc1w  = (const float*)d_in[12];
  const float* fc1b  = (const float*)d_in[13];
  const float* fc2w  = (const float*)d_in[14];
  const float* fc2b  = (const float*)d_in[15];
  const float* mw    = (const float*)d_in[16];
  const float* mb    = (const float*)d_in[17];
  const float* lw    = (const float*)d_in[18];
  const float* lb    = (const float*)d_in[19];

  const int* e_src = eidx;        // edge_index[0]
  const int* e_dst = eidx + NE;   // edge_index[1]

  char* p = (char*)d_ws;
  auto alloc = [&](size_t bytes){ char* r = p; p += align256(bytes); return r; };
  int*   cntc   = (int*)  alloc((size_t)NC*CPAD*4);   // contiguous with gsum
  float* gsum   = (float*)alloc((size_t)NB*GD*4);
  int*   basec  = (int*)  alloc((size_t)NC*CPAD*4);
  int*   tot    = (int*)  alloc((size_t)CPAD*4);
  unsigned short* rank = (unsigned short*)alloc((size_t)NE*2);
  unsigned short* ssrc = (unsigned short*)alloc((size_t)NE*2);
  unsigned char*  fA8 = (unsigned char*) alloc((size_t)NN2*GH);    // fp8 [NN2,128]
  unsigned char*  fB8 = (unsigned char*) alloc((size_t)NN2*GH);    // fp8 [NN2,128]
  unsigned short* fS  = (unsigned short*)alloc((size_t)NN*GH*2);   // bf16 [NN,128]
  unsigned char*  fC8 = (unsigned char*) alloc((size_t)NN*GD);     // fp8 [NN,64]
  unsigned char*  fD8 = (unsigned char*) alloc((size_t)NN*GD);     // fp8 [NN,64]
  unsigned short* fS2 = (unsigned short*)alloc((size_t)NN*GD*2);   // bf16 [NN,64]

  hipMemsetAsync(cntc, 0, (size_t)NC*CPAD*4 + (size_t)NB*GD*4, stream);

  dim3 b256(256);
  k_histgemm1<<<dim3(EB + MB*4), b256, 0, stream>>>(e_dst, cntc, rank, x, g1w1, fA8, fB8);
  k_scan1 <<<dim3(1), dim3(1024), 0, stream>>>(cntc, basec, tot);
  k_place <<<dim3(EB), b256, 0, stream>>>(e_src, e_dst, basec, rank, ssrc);

  k_edge1<<<dim3(NN/8), b256, 0, stream>>>(fA8, fB8, g1b1, basec, tot, ssrc, fS);
  k_mlp2<<<dim3(MB), b256, 0, stream>>>(fS, g1w2, g2w1, tot, g1b2, fC8, fD8);
  k_edge2<<<dim3(NN/16), b256, 0, stream>>>(fC8, fD8, g2b1, basec, tot, ssrc, fS2);
  k_gemm4gs<<<dim3(MB), b256, 0, stream>>>(fS2, g2w2, tot, g2b2, nb, gsum);
  k_head<<<dim3(NB), b256, 0, stream>>>(state, gsum, nb, fc1w, fc1b, fc2w, fc2b,
                                        mw, mb, lw, lb, (float*)d_out);
}

// Round 17
// 266.768 us; speedup vs baseline: 2.1463x; 2.1463x over previous
//
#include <hip/hip_runtime.h>

#define NN 50000      // nodes
#define NN2 50048     // nodes padded to 64
#define NE 800000     // edges
#define NB 128        // graphs / batch
#define SD 64         // state dim / node dim
#define GH 128        // gnn layer1 width
#define GD 64         // gnn layer2 width
#define HID 256       // actor hidden
#define AD 8          // action dim
#define CPAD 53248    // cnt/offs padded: 1024*52
#define EB 391        // edge blocks (2048 edges each)
#define MB 782        // node tile blocks (64 rows each)
#define BST 66        // B-tile LDS stride (shorts), 33 ints: conflict-free
#define BST2 130      // mlp2 B-tile stride (shorts), 65 ints

static inline size_t align256(size_t x){ return (x + 255) & ~size_t(255); }

typedef __attribute__((ext_vector_type(8))) short short8v;
typedef __attribute__((ext_vector_type(4))) float f32x4;
typedef __attribute__((ext_vector_type(2))) float f32x2;

__device__ inline unsigned short f2bf(float f){  // RNE
  unsigned u = __builtin_bit_cast(unsigned, f);
  return (unsigned short)((u + 0x7FFFu + ((u >> 16) & 1u)) >> 16);
}
__device__ inline float bf2f(unsigned short h){
  return __builtin_bit_cast(float, ((unsigned)h) << 16);
}
__device__ inline int pk2bf(float a, float b){
  return (int)((unsigned)f2bf(a) | ((unsigned)f2bf(b) << 16));
}
// fp8 e4m3 HW converts
__device__ inline f32x2 fp8x2_to_f32(unsigned short u){
  return __builtin_amdgcn_cvt_pk_f32_fp8((int)u, false);
}
__device__ inline unsigned char f32_to_fp8(float v){
  return (unsigned char)(__builtin_amdgcn_cvt_pk_fp8_f32(v, v, 0, false) & 0xFF);
}
__device__ inline unsigned pack4_fp8(float a, float b, float c, float d){
  int w = __builtin_amdgcn_cvt_pk_fp8_f32(a, b, 0, false);
  w = __builtin_amdgcn_cvt_pk_fp8_f32(c, d, w, true);
  return (unsigned)w;
}

// ------- fused: hist (blocks [0,EB)) ∥ layer-1 GEMM (blocks [EB,EB+4*MB)) -------
// gemm: Out = fp8(x @ w1-half); x fp32 [NN,64], w1 fp32 [128,128] (rows z*64..)
__global__ __launch_bounds__(256)
void k_histgemm1(const int* __restrict__ edst, int* __restrict__ cnt,
                 unsigned short* __restrict__ rank,
                 const float* __restrict__ x, const float* __restrict__ w1,
                 unsigned char* __restrict__ fA8, unsigned char* __restrict__ fB8)
{
  if (blockIdx.x < EB){
    int e = blockIdx.x*2048 + threadIdx.x;
    #pragma unroll
    for (int j = 0; j < 8; ++j){
      int ee = e + j*256;
      if (ee < NE) rank[ee] = (unsigned short)atomicAdd(&cnt[edst[ee]], 1);
    }
    return;
  }
  int idx = blockIdx.x - EB;           // 0..3127
  int m0 = (idx >> 2) * 64;
  int n0 = (idx & 1) * 64;
  int z  = (idx >> 1) & 1;
  const float* W = w1 + (size_t)z*64*GH;
  unsigned char* Out = z ? fB8 : fA8;

  __shared__ short Ah[64*40];
  __shared__ short Bh[32*BST];          // [k][n], stride 66
  __shared__ float Ts[64*65];
  int tid = threadIdx.x;
  int w = tid >> 6, lane = tid & 63, l15 = tid & 15, quad = lane >> 4;
  f32x4 acc[4];
  #pragma unroll
  for (int t = 0; t < 4; ++t) acc[t] = (f32x4){0.f,0.f,0.f,0.f};

  #pragma unroll
  for (int k0 = 0; k0 < 64; k0 += 32){
    #pragma unroll
    for (int i = 0; i < 2; ++i){       // A: x fp32 -> bf16 [m][k]
      int s = tid + i*256;
      int m = s >> 3, q = s & 7;
      float4 v = make_float4(0.f,0.f,0.f,0.f);
      if (m0 + m < NN) v = *reinterpret_cast<const float4*>(&x[(size_t)(m0+m)*SD + k0 + q*4]);
      short4 h4;
      h4.x = (short)f2bf(v.x); h4.y = (short)f2bf(v.y);
      h4.z = (short)f2bf(v.z); h4.w = (short)f2bf(v.w);
      *reinterpret_cast<short4*>(&Ah[m*40 + q*4]) = h4;
    }
    #pragma unroll
    for (int i = 0; i < 2; ++i){       // B: W fp32 -> bf16 [k][n] (conflict-free)
      int s = tid + i*256;
      int r = s >> 4, cq = s & 15;
      float4 v = *reinterpret_cast<const float4*>(&W[(size_t)(k0+r)*GH + n0 + cq*4]);
      *reinterpret_cast<int*>(&Bh[r*BST + cq*4])     = pk2bf(v.x, v.y);
      *reinterpret_cast<int*>(&Bh[r*BST + cq*4 + 2]) = pk2bf(v.z, v.w);
    }
    __syncthreads();
    short8v ah = *reinterpret_cast<short8v*>(&Ah[(w*16 + l15)*40 + quad*8]);
    #pragma unroll
    for (int t = 0; t < 4; ++t){
      short8v bh;
      #pragma unroll
      for (int j = 0; j < 8; ++j)
        bh[j] = Bh[(quad*8 + j)*BST + t*16 + l15];
      acc[t] = __builtin_amdgcn_mfma_f32_16x16x32_bf16(ah, bh, acc[t], 0, 0, 0);
    }
    __syncthreads();
  }
  #pragma unroll
  for (int r = 0; r < 4; ++r){
    int ml = w*16 + quad*4 + r;
    #pragma unroll
    for (int t = 0; t < 4; ++t)
      Ts[ml*65 + t*16 + l15] = acc[t][r];
  }
  __syncthreads();
  int row = tid >> 2, seg = tid & 3;
  const float* tr = &Ts[row*65 + seg*16];
  uint4 o;
  o.x = pack4_fp8(tr[0], tr[1], tr[2], tr[3]);
  o.y = pack4_fp8(tr[4], tr[5], tr[6], tr[7]);
  o.z = pack4_fp8(tr[8], tr[9], tr[10], tr[11]);
  o.w = pack4_fp8(tr[12], tr[13], tr[14], tr[15]);
  *reinterpret_cast<uint4*>(&Out[(size_t)(m0+row)*GH + n0 + seg*16]) = o;
}

// single-kernel scan: 1 block x 1024 threads, 52 ints/thread (int4 ILP)
__global__ __launch_bounds__(1024)
void k_scan1(const int* __restrict__ cnt, int* __restrict__ offs){
  __shared__ int sm[1024];
  int t = threadIdx.x;
  int4 v[13];
  const int4* c4 = reinterpret_cast<const int4*>(cnt);
  #pragma unroll
  for (int j = 0; j < 13; ++j) v[j] = c4[t*13 + j];
  int s = 0;
  #pragma unroll
  for (int j = 0; j < 13; ++j) s += v[j].x + v[j].y + v[j].z + v[j].w;
  sm[t] = s; __syncthreads();
  for (int d = 1; d < 1024; d <<= 1){
    int add = (t >= d) ? sm[t - d] : 0;
    __syncthreads();
    sm[t] += add;
    __syncthreads();
  }
  int run = sm[t] - s;   // exclusive
  int4* o4 = reinterpret_cast<int4*>(offs);
  #pragma unroll
  for (int j = 0; j < 13; ++j){
    int4 o;
    o.x = run; run += v[j].x;
    o.y = run; run += v[j].y;
    o.z = run; run += v[j].z;
    o.w = run; run += v[j].w;
    o4[t*13 + j] = o;
  }
}

__global__ void k_place(const int* __restrict__ esrc, const int* __restrict__ edst,
                        const int* __restrict__ offs,
                        const unsigned short* __restrict__ rank,
                        unsigned short* __restrict__ ssrc){
  int e = blockIdx.x*2048 + threadIdx.x;
  #pragma unroll
  for (int j = 0; j < 8; ++j){
    int ee = e + j*256;
    if (ee < NE) ssrc[offs[edst[ee]] + (int)rank[ee]] = (unsigned short)esrc[ee];
  }
}

// ------- edge agg layer 1: fp8 gather, 4 ch/lane (32 lanes/node), 8 nodes/block ------
__global__ __launch_bounds__(256)
void k_edge1(const unsigned char* __restrict__ A, const unsigned char* __restrict__ Bm,
             const float* __restrict__ b1, const int* __restrict__ offs,
             const int* __restrict__ cnt, const unsigned short* __restrict__ ssrc,
             unsigned short* __restrict__ S)
{
  int v = blockIdx.x*8 + (threadIdx.x >> 5);
  int c4 = threadIdx.x & 31;          // channels 4*c4 .. 4*c4+3
  int beg = offs[v], n = cnt[v];
  float s0=0.f, s1=0.f, s2=0.f, s3=0.f;
  if (n > 0){
    unsigned au = *reinterpret_cast<const unsigned*>(&A[(size_t)v*GH + 4*c4]);
    f32x2 a01 = fp8x2_to_f32((unsigned short)(au & 0xFFFFu));
    f32x2 a23 = fp8x2_to_f32((unsigned short)(au >> 16));
    float4 bb = *reinterpret_cast<const float4*>(&b1[4*c4]);
    float ax0 = a01.x + bb.x, ax1 = a01.y + bb.y;
    float ax2 = a23.x + bb.z, ax3 = a23.y + bb.w;
    for (int i = 0; i < n; i += 8){
      int ss[8];
      #pragma unroll
      for (int j = 0; j < 8; ++j)
        ss[j] = (i + j < n) ? (int)ssrc[beg + i + j] : (int)ssrc[beg];
      unsigned bu[8];
      #pragma unroll
      for (int j = 0; j < 8; ++j)
        bu[j] = *reinterpret_cast<const unsigned*>(&Bm[(size_t)ss[j]*GH + 4*c4]);
      #pragma unroll
      for (int j = 0; j < 8; ++j){
        f32x2 b01 = fp8x2_to_f32((unsigned short)(bu[j] & 0xFFFFu));
        f32x2 b23 = fp8x2_to_f32((unsigned short)(bu[j] >> 16));
        float live = (i + j < n) ? 1.f : 0.f;
        s0 += live * fmaxf(ax0 + b01.x, 0.f);
        s1 += live * fmaxf(ax1 + b01.y, 0.f);
        s2 += live * fmaxf(ax2 + b23.x, 0.f);
        s3 += live * fmaxf(ax3 + b23.y, 0.f);
      }
    }
  }
  ushort4 o; o.x = f2bf(s0); o.y = f2bf(s1); o.z = f2bf(s2); o.w = f2bf(s3);
  *reinterpret_cast<ushort4*>(&S[(size_t)v*GH + 4*c4]) = o;
}

// ---- fused GNN-layer MLP: h = relu(mean(fS@W2)); C|D = h@W3 (fp8 out), fp32 W ----
__global__ __launch_bounds__(256)
void k_mlp2(const unsigned short* __restrict__ In,   // fS [NN,128] bf16
            const float* __restrict__ W2,            // [128,128] fp32
            const float* __restrict__ W3,            // [256,64] fp32
            const int* __restrict__ cnt, const float* __restrict__ b2,
            unsigned char* __restrict__ fC, unsigned char* __restrict__ fD)
{
  __shared__ short Ah[64*40];
  __shared__ short Bh[32*BST2];        // [k][n(=128)], stride 130
  __shared__ unsigned short Hs[64*136];
  int tid = threadIdx.x;
  int w = tid >> 6, lane = tid & 63, l15 = tid & 15, quad = lane >> 4;
  int m0 = blockIdx.x*64;

  f32x4 acc[8];
  #pragma unroll
  for (int t = 0; t < 8; ++t) acc[t] = (f32x4){0.f,0.f,0.f,0.f};

  for (int k0 = 0; k0 < 128; k0 += 32){
    { int m = tid >> 2, o = tid & 3;
      short8v v = (short8v)(short)0;
      if (m0 + m < NN)
        v = *reinterpret_cast<const short8v*>(&In[(size_t)(m0+m)*GH + k0 + o*8]);
      *reinterpret_cast<short8v*>(&Ah[m*40 + o*8]) = v;
    }
    #pragma unroll
    for (int i = 0; i < 4; ++i){       // W2 fp32 -> bf16 [k][n] (conflict-free)
      int s = tid + i*256;             // 0..1023
      int r = s >> 5, cq = s & 31;
      float4 v = *reinterpret_cast<const float4*>(&W2[(size_t)(k0+r)*GH + cq*4]);
      *reinterpret_cast<int*>(&Bh[r*BST2 + cq*4])     = pk2bf(v.x, v.y);
      *reinterpret_cast<int*>(&Bh[r*BST2 + cq*4 + 2]) = pk2bf(v.z, v.w);
    }
    __syncthreads();
    short8v ah = *reinterpret_cast<short8v*>(&Ah[(w*16 + l15)*40 + quad*8]);
    #pragma unroll
    for (int t = 0; t < 8; ++t){
      short8v bh;
      #pragma unroll
      for (int j = 0; j < 8; ++j)
        bh[j] = Bh[(quad*8 + j)*BST2 + t*16 + l15];
      acc[t] = __builtin_amdgcn_mfma_f32_16x16x32_bf16(ah, bh, acc[t], 0, 0, 0);
    }
    __syncthreads();
  }
  #pragma unroll
  for (int r = 0; r < 4; ++r){
    int ml = w*16 + quad*4 + r;
    int m = m0 + ml;
    float fcnt = 0.f, inv = 1.f;
    if (m < NN){ fcnt = (float)cnt[m]; inv = 1.f / fmaxf(fcnt, 1.f); }
    #pragma unroll
    for (int t = 0; t < 8; ++t){
      int col = t*16 + l15;
      float v = (acc[t][r] + fcnt * b2[col]) * inv;
      Hs[ml*136 + col] = f2bf(fmaxf(v, 0.f));
    }
  }
  __syncthreads();

  f32x4 acc2[8];
  #pragma unroll
  for (int t = 0; t < 8; ++t) acc2[t] = (f32x4){0.f,0.f,0.f,0.f};
  for (int k0 = 0; k0 < 128; k0 += 32){
    #pragma unroll
    for (int i = 0; i < 4; ++i){       // W3 fp32 halves -> bf16 [k][n] (n<64=C)
      int s = tid + i*256;             // 0..1023
      int r = s >> 5, cq = s & 31;
      int half = cq >> 4, cg = cq & 15;
      float4 v = *reinterpret_cast<const float4*>(&W3[(size_t)(half*128 + k0 + r)*GD + cg*4]);
      *reinterpret_cast<int*>(&Bh[r*BST2 + cq*4])     = pk2bf(v.x, v.y);
      *reinterpret_cast<int*>(&Bh[r*BST2 + cq*4 + 2]) = pk2bf(v.z, v.w);
    }
    __syncthreads();
    short8v ah = *reinterpret_cast<short8v*>(&Hs[(w*16 + l15)*136 + k0 + quad*8]);
    #pragma unroll
    for (int t = 0; t < 8; ++t){
      short8v bh;
      #pragma unroll
      for (int j = 0; j < 8; ++j)
        bh[j] = Bh[(quad*8 + j)*BST2 + t*16 + l15];
      acc2[t] = __builtin_amdgcn_mfma_f32_16x16x32_bf16(ah, bh, acc2[t], 0, 0, 0);
    }
    __syncthreads();
  }
  #pragma unroll
  for (int r = 0; r < 4; ++r){
    int m = m0 + w*16 + quad*4 + r;
    if (m >= NN) continue;
    #pragma unroll
    for (int t = 0; t < 8; ++t){
      int col = t*16 + l15;
      unsigned char o = f32_to_fp8(acc2[t][r]);
      if (col < 64) fC[(size_t)m*GD + col] = o;
      else          fD[(size_t)m*GD + col - 64] = o;
    }
  }
}

// ------- edge agg layer 2: fp8 gather, 4 ch/lane (16 lanes/node), 16 nodes/block -----
__global__ __launch_bounds__(256)
void k_edge2(const unsigned char* __restrict__ C, const unsigned char* __restrict__ D,
             const float* __restrict__ b1, const int* __restrict__ offs,
             const int* __restrict__ cnt, const unsigned short* __restrict__ ssrc,
             unsigned short* __restrict__ S2)
{
  int v = blockIdx.x*16 + (threadIdx.x >> 4);
  int c4 = threadIdx.x & 15;          // channels 4*c4 .. 4*c4+3
  int beg = offs[v], n = cnt[v];
  float s0=0.f, s1=0.f, s2=0.f, s3=0.f;
  if (n > 0){
    unsigned au = *reinterpret_cast<const unsigned*>(&C[(size_t)v*GD + 4*c4]);
    f32x2 a01 = fp8x2_to_f32((unsigned short)(au & 0xFFFFu));
    f32x2 a23 = fp8x2_to_f32((unsigned short)(au >> 16));
    float4 bb = *reinterpret_cast<const float4*>(&b1[4*c4]);
    float ax0 = a01.x + bb.x, ax1 = a01.y + bb.y;
    float ax2 = a23.x + bb.z, ax3 = a23.y + bb.w;
    for (int i = 0; i < n; i += 8){
      int ss[8];
      #pragma unroll
      for (int j = 0; j < 8; ++j)
        ss[j] = (i + j < n) ? (int)ssrc[beg + i + j] : (int)ssrc[beg];
      unsigned du[8];
      #pragma unroll
      for (int j = 0; j < 8; ++j)
        du[j] = *reinterpret_cast<const unsigned*>(&D[(size_t)ss[j]*GD + 4*c4]);
      #pragma unroll
      for (int j = 0; j < 8; ++j){
        f32x2 d01 = fp8x2_to_f32((unsigned short)(du[j] & 0xFFFFu));
        f32x2 d23 = fp8x2_to_f32((unsigned short)(du[j] >> 16));
        float live = (i + j < n) ? 1.f : 0.f;
        s0 += live * fmaxf(ax0 + d01.x, 0.f);
        s1 += live * fmaxf(ax1 + d01.y, 0.f);
        s2 += live * fmaxf(ax2 + d23.x, 0.f);
        s3 += live * fmaxf(ax3 + d23.y, 0.f);
      }
    }
  }
  ushort4 o; o.x = f2bf(s0); o.y = f2bf(s1); o.z = f2bf(s2); o.w = f2bf(s3);
  *reinterpret_cast<ushort4*>(&S2[(size_t)v*GD + 4*c4]) = o;
}

// ------- final GEMM: h2 = mean(fS2@W4)+b, graph-sum epilogue into gsum (fp32 W) ------
__global__ __launch_bounds__(256)
void k_gemm4gs(const unsigned short* __restrict__ In,  // fS2 [NN,64] bf16
               const float* __restrict__ W4,           // [64,64] fp32
               const int* __restrict__ cnt, const float* __restrict__ bias,
               const int* __restrict__ nb, float* __restrict__ gsum)
{
  __shared__ short Ah[64*40];
  __shared__ short Bh[32*BST];         // [k][n], stride 66
  __shared__ float Ts[64*65];
  int tid = threadIdx.x;
  int w = tid >> 6, lane = tid & 63, l15 = tid & 15, quad = lane >> 4;
  int m0 = blockIdx.x*64;
  f32x4 acc[4];
  #pragma unroll
  for (int t = 0; t < 4; ++t) acc[t] = (f32x4){0.f,0.f,0.f,0.f};

  #pragma unroll
  for (int k0 = 0; k0 < 64; k0 += 32){
    { int m = tid >> 2, o = tid & 3;
      short8v v = (short8v)(short)0;
      if (m0 + m < NN)
        v = *reinterpret_cast<const short8v*>(&In[(size_t)(m0+m)*GD + k0 + o*8]);
      *reinterpret_cast<short8v*>(&Ah[m*40 + o*8]) = v;
    }
    #pragma unroll
    for (int i = 0; i < 2; ++i){       // W4 fp32 -> bf16 [k][n] (conflict-free)
      int s = tid + i*256;
      int r = s >> 4, cq = s & 15;
      float4 v = *reinterpret_cast<const float4*>(&W4[(size_t)(k0+r)*GD + cq*4]);
      *reinterpret_cast<int*>(&Bh[r*BST + cq*4])     = pk2bf(v.x, v.y);
      *reinterpret_cast<int*>(&Bh[r*BST + cq*4 + 2]) = pk2bf(v.z, v.w);
    }
    __syncthreads();
    short8v ah = *reinterpret_cast<short8v*>(&Ah[(w*16 + l15)*40 + quad*8]);
    #pragma unroll
    for (int t = 0; t < 4; ++t){
      short8v bh;
      #pragma unroll
      for (int j = 0; j < 8; ++j)
        bh[j] = Bh[(quad*8 + j)*BST + t*16 + l15];
      acc[t] = __builtin_amdgcn_mfma_f32_16x16x32_bf16(ah, bh, acc[t], 0, 0, 0);
    }
    __syncthreads();
  }
  #pragma unroll
  for (int r = 0; r < 4; ++r){
    int ml = w*16 + quad*4 + r;
    int m = m0 + ml;
    float fcnt = 0.f, inv = 1.f;
    if (m < NN){ fcnt = (float)cnt[m]; inv = 1.f / fmaxf(fcnt, 1.f); }
    #pragma unroll
    for (int t = 0; t < 4; ++t){
      int n = t*16 + l15;
      Ts[ml*65 + n] = (acc[t][r] + fcnt * bias[n]) * inv;
    }
  }
  __syncthreads();
  int col = tid & 63, rg = tid >> 6;
  float a = 0.f; int cur = -1;
  for (int rr = rg*16; rr < rg*16 + 16; ++rr){
    int m = m0 + rr; if (m >= NN) break;
    int g = nb[m];
    if (g != cur){ if (cur >= 0) atomicAdd(&gsum[cur*GD + col], a); cur = g; a = 0.f; }
    a += Ts[rr*65 + col];
  }
  if (cur >= 0) atomicAdd(&gsum[cur*GD + col], a);
}

// ---------------- actor head: one block per batch row (divide fused here) -----
__global__ __launch_bounds__(256)
void k_head(const float* __restrict__ state, const float* __restrict__ gsum,
            const int* __restrict__ nb,
            const float* __restrict__ fc1w, const float* __restrict__ fc1b,
            const float* __restrict__ fc2w, const float* __restrict__ fc2b,
            const float* __restrict__ mw, const float* __restrict__ mb,
            const float* __restrict__ lw, const float* __restrict__ lb,
            float* __restrict__ out)
{
  int b = blockIdx.x, t = threadIdx.x;
  __shared__ float z[SD + GD];
  __shared__ float h1[HID];
  __shared__ float h2[HID];
  __shared__ int bounds[2];
  if (t < 2){
    int target = b + t;
    int lo = 0, hi = NN;
    while (lo < hi){ int mid = (lo + hi) >> 1; if (nb[mid] < target) lo = mid + 1; else hi = mid; }
    bounds[t] = lo;
  }
  if (t < SD) z[t] = state[b*SD + t];
  __syncthreads();
  if (t >= SD && t < SD + GD){
    float n = (float)(bounds[1] - bounds[0]);
    z[t] = gsum[b*GD + (t - SD)] / fmaxf(n, 1.f);
  }
  __syncthreads();
  float acc = fc1b[t];
  for (int k = 0; k < SD + GD; ++k) acc = fmaf(z[k], fc1w[k*HID + t], acc);
  h1[t] = fmaxf(acc, 0.f);
  __syncthreads();
  acc = fc2b[t];
  for (int k = 0; k < HID; ++k) acc = fmaf(h1[k], fc2w[k*HID + t], acc);
  h2[t] = fmaxf(acc, 0.f);
  __syncthreads();
  if (t < AD){
    float m = mb[t];
    for (int k = 0; k < HID; ++k) m = fmaf(h2[k], mw[k*AD + t], m);
    out[b*AD + t] = m;
  } else if (t < 2*AD){
    int j = t - AD;
    float l = lb[j];
    for (int k = 0; k < HID; ++k) l = fmaf(h2[k], lw[k*AD + j], l);
    out[NB*AD + b*AD + j] = fminf(fmaxf(l, -20.f), 2.f);
  }
}

extern "C" void kernel_launch(void* const* d_in, const int* in_sizes, int n_in,
                              void* d_out, int out_size, void* d_ws, size_t ws_size,
                              hipStream_t stream)
{
  const float* state = (const float*)d_in[0];
  const float* x     = (const float*)d_in[1];
  const int*   eidx  = (const int*)  d_in[2];
  const int*   nb    = (const int*)  d_in[3];
  const float* g1w1  = (const float*)d_in[4];
  const float* g1b1  = (const float*)d_in[5];
  const float* g1w2  = (const float*)d_in[6];
  const float* g1b2  = (const float*)d_in[7];
  const float* g2w1  = (const float*)d_in[8];
  const float* g2b1  = (const float*)d_in[9];
  const float* g2w2  = (const float*)d_in[10];
  const float* g2b2  = (const float*)d_in[11];
  const float* fc1w  = (const float*)d_in[12];
  const float* fc1b  = (const float*)d_in[13];
  const float* fc2w  = (const float*)d_in[14];
  const float* fc2b  = (const float*)d_in[15];
  const float* mw    = (const float*)d_in[16];
  const float* mb    = (const float*)d_in[17];
  const float* lw    = (const float*)d_in[18];
  const float* lb    = (const float*)d_in[19];

  const int* e_src = eidx;        // edge_index[0]
  const int* e_dst = eidx + NE;   // edge_index[1]

  char* p = (char*)d_ws;
  auto alloc = [&](size_t bytes){ char* r = p; p += align256(bytes); return r; };
  int*   cnt    = (int*)  alloc((size_t)CPAD*4);    // contiguous with gsum
  float* gsum   = (float*)alloc((size_t)NB*GD*4);
  int*   offs   = (int*)  alloc((size_t)CPAD*4);
  unsigned short* rank = (unsigned short*)alloc((size_t)NE*2);
  unsigned short* ssrc = (unsigned short*)alloc((size_t)NE*2);
  unsigned char*  fA8 = (unsigned char*) alloc((size_t)NN2*GH);    // fp8 [NN2,128]
  unsigned char*  fB8 = (unsigned char*) alloc((size_t)NN2*GH);    // fp8 [NN2,128]
  unsigned short* fS  = (unsigned short*)alloc((size_t)NN*GH*2);   // bf16 [NN,128]
  unsigned char*  fC8 = (unsigned char*) alloc((size_t)NN*GD);     // fp8 [NN,64]
  unsigned char*  fD8 = (unsigned char*) alloc((size_t)NN*GD);     // fp8 [NN,64]
  unsigned short* fS2 = (unsigned short*)alloc((size_t)NN*GD*2);   // bf16 [NN,64]

  hipMemsetAsync(cnt, 0, (size_t)CPAD*4 + (size_t)NB*GD*4, stream);

  dim3 b256(256);
  k_histgemm1<<<dim3(EB + MB*4), b256, 0, stream>>>(e_dst, cnt, rank, x, g1w1, fA8, fB8);
  k_scan1 <<<dim3(1), dim3(1024), 0, stream>>>(cnt, offs);
  k_place <<<dim3(EB), b256, 0, stream>>>(e_src, e_dst, offs, rank, ssrc);

  k_edge1<<<dim3(NN/8), b256, 0, stream>>>(fA8, fB8, g1b1, offs, cnt, ssrc, fS);
  k_mlp2<<<dim3(MB), b256, 0, stream>>>(fS, g1w2, g2w1, cnt, g1b2, fC8, fD8);
  k_edge2<<<dim3(NN/16), b256, 0, stream>>>(fC8, fD8, g2b1, offs, cnt, ssrc, fS2);
  k_gemm4gs<<<dim3(MB), b256, 0, stream>>>(fS2, g2w2, cnt, g2b2, nb, gsum);
  k_head<<<dim3(NB), b256, 0, stream>>>(state, gsum, nb, fc1w, fc1b, fc2w, fc2b,
                                        mw, mb, lw, lb, (float*)d_out);
}